// Round 8
// baseline (693.976 us; speedup 1.0000x reference)
//
#include <hip/hip_runtime.h>

// Problem constants: B=4, S=1024, D=1024, H=16, HD=64
constexpr int Bc = 4, Sc = 1024, Dc = 1024, Hc = 16, HDc = 64;
constexpr long BSD = (long)Bc * Sc * Dc;      // 4,194,304
constexpr long MM  = (long)Dc * Dc;           // 1,048,576

typedef __attribute__((ext_vector_type(8))) short bf16x8;   // 8 bf16 = 4 VGPRs
typedef __attribute__((ext_vector_type(4))) float f32x4;
typedef unsigned int u32;

__device__ inline ushort f2bf(float f) {  // round-to-nearest-even
    union { float f; unsigned i; } v; v.f = f;
    unsigned lsb = (v.i >> 16) & 1;
    v.i += 0x7fffu + lsb;
    return (ushort)(v.i >> 16);
}

// ---------------------------------------------------------------------------
// One-launch fp32 -> bf16 convert of q,k,v,Wq,Wk,Wv,Wo into ws.
// ---------------------------------------------------------------------------
__global__ __launch_bounds__(256)
void cvt_all(const float* __restrict__ q, const float* __restrict__ k,
             const float* __restrict__ v, const float* __restrict__ Wq,
             const float* __restrict__ Wk, const float* __restrict__ Wv,
             const float* __restrict__ Wo, ushort* __restrict__ dst)
{
    const int t = blockIdx.y;
    const long n = (t < 3) ? BSD : MM;
    const long i = ((long)blockIdx.x * 256 + threadIdx.x) * 8;
    if (i >= n) return;
    const float* src; long off;
    switch (t) {
        case 0: src = q;  off = 0;            break;
        case 1: src = k;  off = BSD;          break;
        case 2: src = v;  off = 2 * BSD;      break;
        case 3: src = Wq; off = 3 * BSD;      break;
        case 4: src = Wk; off = 3 * BSD + MM; break;
        case 5: src = Wv; off = 3 * BSD + 2 * MM; break;
        default: src = Wo; off = 3 * BSD + 3 * MM; break;
    }
    f32x4 a = *(const f32x4*)(src + i);
    f32x4 b = *(const f32x4*)(src + i + 4);
    bf16x8 r;
    #pragma unroll
    for (int j = 0; j < 4; j++) { r[j] = (short)f2bf(a[j]); r[j + 4] = (short)f2bf(b[j]); }
    *(bf16x8*)(dst + off + i) = r;
}

// ---------------------------------------------------------------------------
// Stage one 128x32 bf16 tile into LDS via global_load_lds (width 16).
// ---------------------------------------------------------------------------
__device__ inline void stage_tile(const ushort* __restrict__ G, int ld, int rowbase,
                                  int kt, ushort* lds, int wave, int lane)
{
    #pragma unroll
    for (int j = 0; j < 2; j++) {
        const int c = wave * 128 + j * 64 + lane;
        const int row = c >> 2, k8 = c & 3;
        const ushort* g = G + (long)(rowbase + row) * ld + kt + k8 * 8;
        ushort* l = lds + (wave * 128 + j * 64) * 8;   // wave-uniform base
        __builtin_amdgcn_global_load_lds(
            (const __attribute__((address_space(1))) u32*)(const void*)g,
            (__attribute__((address_space(3))) u32*)(void*)l, 16, 0, 0);
    }
}

// ---------------------------------------------------------------------------
// Shared m97-style main loop: acc[4][4] += A[128xK] * Bt[128xK]^T tile-product.
// ---------------------------------------------------------------------------
__device__ inline void gemm_core(const ushort* __restrict__ A, int lda,
                                 const ushort* __restrict__ Bt, int ldb, int K,
                                 int mtile, int ntile,
                                 ushort (*As)[128 * 32], ushort (*Bs)[128 * 32],
                                 f32x4 (*acc)[4], int wave, int lane)
{
    const int l15 = lane & 15, quad = lane >> 4;
    const int wr = wave >> 1, wc = wave & 1;

    stage_tile(A,  lda, mtile, 0, As[0], wave, lane);
    stage_tile(Bt, ldb, ntile, 0, Bs[0], wave, lane);
    __syncthreads();

    int buf = 0;
    for (int kt = 0; kt < K; kt += 32) {
        if (kt + 32 < K) {
            stage_tile(A,  lda, mtile, kt + 32, As[buf ^ 1], wave, lane);
            stage_tile(Bt, ldb, ntile, kt + 32, Bs[buf ^ 1], wave, lane);
        }
        bf16x8 af[4], bfr[4];
        #pragma unroll
        for (int mt = 0; mt < 4; mt++)
            af[mt] = *(const bf16x8*)(As[buf] + (wr * 64 + mt * 16 + l15) * 32 + quad * 8);
        #pragma unroll
        for (int nt = 0; nt < 4; nt++)
            bfr[nt] = *(const bf16x8*)(Bs[buf] + (wc * 64 + nt * 16 + l15) * 32 + quad * 8);
        #pragma unroll
        for (int mt = 0; mt < 4; mt++)
            #pragma unroll
            for (int nt = 0; nt < 4; nt++)
                acc[mt][nt] = __builtin_amdgcn_mfma_f32_16x16x32_bf16(af[mt], bfr[nt], acc[mt][nt], 0, 0, 0);
        __syncthreads();   // drains prefetch vmcnt + protects LDS reuse
        buf ^= 1;
    }
}

// ---------------------------------------------------------------------------
// Batched Q/K/V projection: grid.z = 0,1,2. z<2: row-major bf16. z==2: Vt scatter.
// ---------------------------------------------------------------------------
__global__ __launch_bounds__(256)
void gemm_qkv(const ushort* __restrict__ ws, const float* __restrict__ bq,
              const float* __restrict__ bk, const float* __restrict__ bv,
              ushort* __restrict__ QK, ushort* __restrict__ Vt)
{
    __shared__ ushort As[2][128 * 32];
    __shared__ ushort Bs[2][128 * 32];

    const int z = blockIdx.z;
    const ushort* A  = ws + (long)z * BSD;
    const ushort* Bt = ws + 3 * BSD + (long)z * MM;
    const float* bias = (z == 0) ? bq : (z == 1) ? bk : bv;

    const int lane = threadIdx.x & 63, wave = threadIdx.x >> 6;
    const int l15 = lane & 15, quad = lane >> 4;
    const int wr = wave >> 1, wc = wave & 1;
    const int mtile = blockIdx.y * 128, ntile = blockIdx.x * 128;

    f32x4 acc[4][4] = {};
    gemm_core(A, Dc, Bt, Dc, Dc, mtile, ntile, As, Bs, acc, wave, lane);

    #pragma unroll
    for (int mt = 0; mt < 4; mt++) {
        #pragma unroll
        for (int nt = 0; nt < 4; nt++) {
            const int col = ntile + wc * 64 + nt * 16 + l15;
            const float bb = bias[col];
            #pragma unroll
            for (int i = 0; i < 4; i++) {
                const int r = mtile + wr * 64 + mt * 16 + quad * 4 + i;
                const float vv = acc[mt][nt][i] + bb;
                if (z < 2) {
                    QK[(long)z * BSD + (long)r * Dc + col] = f2bf(vv);
                } else {
                    const int b = r >> 10, sI = r & 1023;
                    const int hh = col >> 6, dd = col & 63;
                    Vt[(long)((b * Hc + hh) * HDc + dd) * Sc + sI] = f2bf(vv);
                }
            }
        }
    }
}

// ---------------------------------------------------------------------------
// Output projection: out = Ctx @ Wo^T + bo, fp32 out.
// ---------------------------------------------------------------------------
__global__ __launch_bounds__(256)
void gemm_out(const ushort* __restrict__ A, const ushort* __restrict__ Bt,
              const float* __restrict__ bias, float* __restrict__ C)
{
    __shared__ ushort As[2][128 * 32];
    __shared__ ushort Bs[2][128 * 32];

    const int lane = threadIdx.x & 63, wave = threadIdx.x >> 6;
    const int l15 = lane & 15, quad = lane >> 4;
    const int wr = wave >> 1, wc = wave & 1;
    const int mtile = blockIdx.y * 128, ntile = blockIdx.x * 128;

    f32x4 acc[4][4] = {};
    gemm_core(A, Dc, Bt, Dc, Dc, mtile, ntile, As, Bs, acc, wave, lane);

    #pragma unroll
    for (int mt = 0; mt < 4; mt++) {
        #pragma unroll
        for (int nt = 0; nt < 4; nt++) {
            const int col = ntile + wc * 64 + nt * 16 + l15;
            const float bb = bias[col];
            #pragma unroll
            for (int i = 0; i < 4; i++) {
                const int r = mtile + wr * 64 + mt * 16 + quad * 4 + i;
                C[(long)r * Dc + col] = acc[mt][nt][i] + bb;
            }
        }
    }
}

// ---------------------------------------------------------------------------
// Fused scores + mask + softmax + PV — REGISTER-RESIDENT SCORES.
// Counter evidence (R4): 64KB score LDS -> 2 blocks/CU, Occupancy 22.5%,
// MfmaUtil 3.8%, VALUBusy 21% -> latency-bound. Scores never leave the MFMA
// accumulators now: lane holds S[quad*4+i][ct*16+l15] for t=0..15 (64 VGPR).
//  Phase 1: 16x {2 global K loads + 2 MFMA} — no DS ops, no barriers: loads
//           pipeline freely across iterations.
//  Phase 2: softmax in registers: in-lane max/sum over t, shfl_xor over the
//           quad's 16 lanes, 512B LDS exchange across 4 waves (2 barriers).
//           Writes fp32 attn from regs + bf16 P into 32KB LDS (swizzled).
//  Phase 3: ctx = P @ V; A-frag = one swizzled ds_read_b128 per 32-k chunk.
// LDS 33KB, launch_bounds(256,3) -> target 3 blocks/CU (12 waves, was 8).
// ---------------------------------------------------------------------------
__global__ __launch_bounds__(256, 3)
void attn_fused(const ushort* __restrict__ Q, const ushort* __restrict__ Kp,
                const ushort* __restrict__ Vt, const int* __restrict__ mask,
                float* __restrict__ attn, ushort* __restrict__ Ctx)
{
    __shared__ ushort pB[16 * 1024];   // bf16 P, swizzled: 32 KB
    __shared__ float red[2][4][16];    // cross-wave {max,sum} exchange: 512 B

    const int bh = blockIdx.y;
    const int b = bh >> 4, h = bh & 15;
    const int qbase = blockIdx.x * 16;
    const int lane = threadIdx.x & 63;
    const int wave = threadIdx.x >> 6;
    const int l15 = lane & 15, quad = lane >> 4;

    const ushort* Qh = Q  + (long)b * Sc * Dc + h * HDc;
    const ushort* Kh = Kp + (long)b * Sc * Dc + h * HDc;

    const ushort* qrow = Qh + (long)(qbase + l15) * Dc + quad * 8;
    const bf16x8 a0 = *(const bf16x8*)(qrow);
    const bf16x8 a1 = *(const bf16x8*)(qrow + 32);

    // Phase 1: scores into registers. Wave w covers k-cols [w*256, w*256+256).
    // sacc[t][i] = S[row=quad*4+i][col=(wave*16+t)*16+l15]
    f32x4 sacc[16];
    #pragma unroll 4
    for (int t = 0; t < 16; t++) {
        const int ct = wave * 16 + t;
        const ushort* krow = Kh + (long)(ct * 16 + l15) * Dc + quad * 8;
        const bf16x8 b0 = *(const bf16x8*)(krow);
        const bf16x8 b1 = *(const bf16x8*)(krow + 32);
        f32x4 acc = {};
        acc = __builtin_amdgcn_mfma_f32_16x16x32_bf16(a0, b0, acc, 0, 0, 0);
        acc = __builtin_amdgcn_mfma_f32_16x16x32_bf16(a1, b1, acc, 0, 0, 0);
        sacc[t] = acc;
    }

    // mask bit t for this lane's col (wave*16+t)*16 + l15 (col independent of i)
    unsigned mbits = 0;
    #pragma unroll
    for (int t = 0; t < 16; t++)
        if (mask[b * Sc + (wave * 16 + t) * 16 + l15] == 0) mbits |= (1u << t);

    // Phase 2a: scale + mask in place; per-row max over t (in-lane).
    float mx[4] = { -3.0e38f, -3.0e38f, -3.0e38f, -3.0e38f };
    #pragma unroll
    for (int t = 0; t < 16; t++) {
        const bool msk = (mbits >> t) & 1;
        #pragma unroll
        for (int i = 0; i < 4; i++) {
            float s = sacc[t][i] * 0.125f;          // 1/sqrt(64)
            s = msk ? -1e10f : s;
            sacc[t][i] = s;
            mx[i] = fmaxf(mx[i], s);
        }
    }
    // reduce max over the quad's 16 lanes (bits 0-3 of lane id).
    #pragma unroll
    for (int off = 1; off <= 8; off <<= 1)
        #pragma unroll
        for (int i = 0; i < 4; i++) mx[i] = fmaxf(mx[i], __shfl_xor(mx[i], off, 64));
    // cross-wave max exchange.
    if (l15 == 0)
        #pragma unroll
        for (int i = 0; i < 4; i++) red[0][wave][quad * 4 + i] = mx[i];
    __syncthreads();
    #pragma unroll
    for (int i = 0; i < 4; i++) {
        float g = red[0][0][quad * 4 + i];
        #pragma unroll
        for (int w = 1; w < 4; w++) g = fmaxf(g, red[0][w][quad * 4 + i]);
        mx[i] = g;
    }

    // Phase 2b: exp in place + per-row sum; reduce; cross-wave sum exchange.
    float sm[4] = { 0.f, 0.f, 0.f, 0.f };
    #pragma unroll
    for (int t = 0; t < 16; t++)
        #pragma unroll
        for (int i = 0; i < 4; i++) {
            const float e = __expf(sacc[t][i] - mx[i]);
            sacc[t][i] = e;
            sm[i] += e;
        }
    #pragma unroll
    for (int off = 1; off <= 8; off <<= 1)
        #pragma unroll
        for (int i = 0; i < 4; i++) sm[i] += __shfl_xor(sm[i], off, 64);
    if (l15 == 0)
        #pragma unroll
        for (int i = 0; i < 4; i++) red[1][wave][quad * 4 + i] = sm[i];
    __syncthreads();
    float inv[4];
    #pragma unroll
    for (int i = 0; i < 4; i++) {
        float g = red[1][0][quad * 4 + i] + red[1][1][quad * 4 + i]
                + red[1][2][quad * 4 + i] + red[1][3][quad * 4 + i];
        inv[i] = 1.0f / g;
    }

    // Phase 2c: write fp32 attn (from regs) + bf16 P into swizzled LDS.
    // P row r layout: 8B unit u of logical col-chunk c is at c ^ ((r&7)<<1).
    #pragma unroll
    for (int t = 0; t < 16; t++) {
        const int col = (wave * 16 + t) * 16 + l15;
        #pragma unroll
        for (int i = 0; i < 4; i++) {
            const float p = sacc[t][i] * inv[i];
            const int r = quad * 4 + i;
            attn[((long)bh * Sc + qbase + r) * Sc + col] = p;
            const int u = (col >> 2) ^ ((r & 7) << 1);
            pB[r * 1024 + (u << 2) + (col & 3)] = f2bf(p);
        }
    }
    __syncthreads();

    // Phase 3: ctx = P @ V. Wave w owns d-tile [w*16, w*16+16); 4 indep chains.
    f32x4 pacc[4] = {};
    const ushort* prow = pB + l15 * 1024;
    const int sw2 = (l15 & 7) << 1;
    const ushort* Vh = Vt + (long)bh * HDc * Sc + (long)(wave * 16 + l15) * Sc + quad * 8;
    for (int k0 = 0; k0 < Sc; k0 += 128) {
        bf16x8 af[4], bv4[4];
        #pragma unroll
        for (int u = 0; u < 4; u++) {
            const int k = k0 + u * 32 + quad * 8;               // k>>2 is even
            af[u]  = *(const bf16x8*)(prow + (((k >> 2) ^ sw2) << 2));
            bv4[u] = *(const bf16x8*)(Vh + k0 + u * 32);
        }
        __builtin_amdgcn_s_setprio(1);
        #pragma unroll
        for (int u = 0; u < 4; u++)
            pacc[u] = __builtin_amdgcn_mfma_f32_16x16x32_bf16(af[u], bv4[u], pacc[u], 0, 0, 0);
        __builtin_amdgcn_s_setprio(0);
    }
    f32x4 acc;
    #pragma unroll
    for (int i = 0; i < 4; i++) acc[i] = (pacc[0][i] + pacc[1][i]) + (pacc[2][i] + pacc[3][i]);

    const int dcol = h * HDc + wave * 16 + l15;
    #pragma unroll
    for (int i = 0; i < 4; i++) {
        const int r = qbase + quad * 4 + i;
        Ctx[(long)b * Sc * Dc + (long)r * Dc + dcol] = f2bf(acc[i]);
    }
}

// ---------------------------------------------------------------------------
extern "C" void kernel_launch(void* const* d_in, const int* in_sizes, int n_in,
                              void* d_out, int out_size, void* d_ws, size_t ws_size,
                              hipStream_t stream)
{
    const float* q    = (const float*)d_in[0];
    const float* k    = (const float*)d_in[1];
    const float* v    = (const float*)d_in[2];
    const int*   mask = (const int*)  d_in[3];
    const float* Wq   = (const float*)d_in[4];
    const float* bq   = (const float*)d_in[5];
    const float* Wk   = (const float*)d_in[6];
    const float* bk   = (const float*)d_in[7];
    const float* Wv   = (const float*)d_in[8];
    const float* bv   = (const float*)d_in[9];
    const float* Wo   = (const float*)d_in[10];
    const float* bo   = (const float*)d_in[11];

    ushort* ws  = (ushort*)d_ws;
    ushort* Wob = ws + 3 * BSD + 3 * MM;
    ushort* Qp  = ws + 3 * BSD + 4 * MM;     // projected Q bf16
    ushort* Kpp = Qp + BSD;                  // projected K bf16
    ushort* Vt  = Kpp + BSD;                 // Vt[b,h,d,s] bf16
    ushort* Ctx = Vt + BSD;                  // ctx bf16, (B,S,D) layout

    float* out  = (float*)d_out;             // output 0: (B,S,D) fp32
    float* attn = out + BSD;                 // output 1: (B,H,S,S) fp32

    const dim3 blk(256);

    // fp32 -> bf16 converts (one launch, 7 tensors)
    cvt_all<<<dim3(BSD / (256 * 8), 7), blk, 0, stream>>>(q, k, v, Wq, Wk, Wv, Wo, ws);

    // Q,K,V projections batched: grid (8,32,3) = 768 blocks (~3 blocks/CU).
    gemm_qkv<<<dim3(8, 32, 3), blk, 0, stream>>>(ws, bq, bk, bv, Qp, Vt);

    // Fused scores + softmax + PV: writes attn (fp32 output) and Ctx (bf16).
    attn_fused<<<dim3(Sc / 16, Bc * Hc), blk, 0, stream>>>(Qp, Kpp, Vt, mask, attn, Ctx);

    // out = ctx @ Wo^T + bo (fp32 out).
    gemm_out<<<dim3(8, 32), blk, 0, stream>>>(Ctx, Wob, bo, out);
}

// Round 10
// 510.314 us; speedup vs baseline: 1.3599x; 1.3599x over previous
//
#include <hip/hip_runtime.h>

// Problem constants: B=4, S=1024, D=1024, H=16, HD=64
constexpr int Bc = 4, Sc = 1024, Dc = 1024, Hc = 16, HDc = 64;
constexpr long BSD = (long)Bc * Sc * Dc;      // 4,194,304
constexpr long MM  = (long)Dc * Dc;           // 1,048,576

typedef __attribute__((ext_vector_type(8))) short bf16x8;   // 8 bf16 = 4 VGPRs
typedef __attribute__((ext_vector_type(4))) float f32x4;
typedef unsigned int u32;

__device__ inline ushort f2bf(float f) {  // round-to-nearest-even
    union { float f; unsigned i; } v; v.f = f;
    unsigned lsb = (v.i >> 16) & 1;
    v.i += 0x7fffu + lsb;
    return (ushort)(v.i >> 16);
}

// ---------------------------------------------------------------------------
// One-launch fp32 -> bf16 convert of q,k,v,Wq,Wk,Wv,Wo into ws.
// ---------------------------------------------------------------------------
__global__ __launch_bounds__(256)
void cvt_all(const float* __restrict__ q, const float* __restrict__ k,
             const float* __restrict__ v, const float* __restrict__ Wq,
             const float* __restrict__ Wk, const float* __restrict__ Wv,
             const float* __restrict__ Wo, ushort* __restrict__ dst)
{
    const int t = blockIdx.y;
    const long n = (t < 3) ? BSD : MM;
    const long i = ((long)blockIdx.x * 256 + threadIdx.x) * 8;
    if (i >= n) return;
    const float* src; long off;
    switch (t) {
        case 0: src = q;  off = 0;            break;
        case 1: src = k;  off = BSD;          break;
        case 2: src = v;  off = 2 * BSD;      break;
        case 3: src = Wq; off = 3 * BSD;      break;
        case 4: src = Wk; off = 3 * BSD + MM; break;
        case 5: src = Wv; off = 3 * BSD + 2 * MM; break;
        default: src = Wo; off = 3 * BSD + 3 * MM; break;
    }
    f32x4 a = *(const f32x4*)(src + i);
    f32x4 b = *(const f32x4*)(src + i + 4);
    bf16x8 r;
    #pragma unroll
    for (int j = 0; j < 4; j++) { r[j] = (short)f2bf(a[j]); r[j + 4] = (short)f2bf(b[j]); }
    *(bf16x8*)(dst + off + i) = r;
}

// ---------------------------------------------------------------------------
// Stage one 128x32 bf16 tile into LDS via global_load_lds (width 16).
// ---------------------------------------------------------------------------
__device__ inline void stage_tile(const ushort* __restrict__ G, int ld, int rowbase,
                                  int kt, ushort* lds, int wave, int lane)
{
    #pragma unroll
    for (int j = 0; j < 2; j++) {
        const int c = wave * 128 + j * 64 + lane;
        const int row = c >> 2, k8 = c & 3;
        const ushort* g = G + (long)(rowbase + row) * ld + kt + k8 * 8;
        ushort* l = lds + (wave * 128 + j * 64) * 8;   // wave-uniform base
        __builtin_amdgcn_global_load_lds(
            (const __attribute__((address_space(1))) u32*)(const void*)g,
            (__attribute__((address_space(3))) u32*)(void*)l, 16, 0, 0);
    }
}

// ---------------------------------------------------------------------------
// Shared m97-style main loop: acc[4][4] += A[128xK] * Bt[128xK]^T tile-product.
// ---------------------------------------------------------------------------
__device__ inline void gemm_core(const ushort* __restrict__ A, int lda,
                                 const ushort* __restrict__ Bt, int ldb, int K,
                                 int mtile, int ntile,
                                 ushort (*As)[128 * 32], ushort (*Bs)[128 * 32],
                                 f32x4 (*acc)[4], int wave, int lane)
{
    const int l15 = lane & 15, quad = lane >> 4;
    const int wr = wave >> 1, wc = wave & 1;

    stage_tile(A,  lda, mtile, 0, As[0], wave, lane);
    stage_tile(Bt, ldb, ntile, 0, Bs[0], wave, lane);
    __syncthreads();

    int buf = 0;
    for (int kt = 0; kt < K; kt += 32) {
        if (kt + 32 < K) {
            stage_tile(A,  lda, mtile, kt + 32, As[buf ^ 1], wave, lane);
            stage_tile(Bt, ldb, ntile, kt + 32, Bs[buf ^ 1], wave, lane);
        }
        bf16x8 af[4], bfr[4];
        #pragma unroll
        for (int mt = 0; mt < 4; mt++)
            af[mt] = *(const bf16x8*)(As[buf] + (wr * 64 + mt * 16 + l15) * 32 + quad * 8);
        #pragma unroll
        for (int nt = 0; nt < 4; nt++)
            bfr[nt] = *(const bf16x8*)(Bs[buf] + (wc * 64 + nt * 16 + l15) * 32 + quad * 8);
        #pragma unroll
        for (int mt = 0; mt < 4; mt++)
            #pragma unroll
            for (int nt = 0; nt < 4; nt++)
                acc[mt][nt] = __builtin_amdgcn_mfma_f32_16x16x32_bf16(af[mt], bfr[nt], acc[mt][nt], 0, 0, 0);
        __syncthreads();   // drains prefetch vmcnt + protects LDS reuse
        buf ^= 1;
    }
}

// ---------------------------------------------------------------------------
// Batched Q/K/V projection: grid.z = 0,1,2. z<2: row-major bf16. z==2: Vt scatter.
// ---------------------------------------------------------------------------
__global__ __launch_bounds__(256)
void gemm_qkv(const ushort* __restrict__ ws, const float* __restrict__ bq,
              const float* __restrict__ bk, const float* __restrict__ bv,
              ushort* __restrict__ QK, ushort* __restrict__ Vt)
{
    __shared__ ushort As[2][128 * 32];
    __shared__ ushort Bs[2][128 * 32];

    const int z = blockIdx.z;
    const ushort* A  = ws + (long)z * BSD;
    const ushort* Bt = ws + 3 * BSD + (long)z * MM;
    const float* bias = (z == 0) ? bq : (z == 1) ? bk : bv;

    const int lane = threadIdx.x & 63, wave = threadIdx.x >> 6;
    const int l15 = lane & 15, quad = lane >> 4;
    const int wr = wave >> 1, wc = wave & 1;
    const int mtile = blockIdx.y * 128, ntile = blockIdx.x * 128;

    f32x4 acc[4][4] = {};
    gemm_core(A, Dc, Bt, Dc, Dc, mtile, ntile, As, Bs, acc, wave, lane);

    #pragma unroll
    for (int mt = 0; mt < 4; mt++) {
        #pragma unroll
        for (int nt = 0; nt < 4; nt++) {
            const int col = ntile + wc * 64 + nt * 16 + l15;
            const float bb = bias[col];
            #pragma unroll
            for (int i = 0; i < 4; i++) {
                const int r = mtile + wr * 64 + mt * 16 + quad * 4 + i;
                const float vv = acc[mt][nt][i] + bb;
                if (z < 2) {
                    QK[(long)z * BSD + (long)r * Dc + col] = f2bf(vv);
                } else {
                    const int b = r >> 10, sI = r & 1023;
                    const int hh = col >> 6, dd = col & 63;
                    Vt[(long)((b * Hc + hh) * HDc + dd) * Sc + sI] = f2bf(vv);
                }
            }
        }
    }
}

// ---------------------------------------------------------------------------
// Output projection: out = Ctx @ Wo^T + bo, fp32 out.
// ---------------------------------------------------------------------------
__global__ __launch_bounds__(256)
void gemm_out(const ushort* __restrict__ A, const ushort* __restrict__ Bt,
              const float* __restrict__ bias, float* __restrict__ C)
{
    __shared__ ushort As[2][128 * 32];
    __shared__ ushort Bs[2][128 * 32];

    const int lane = threadIdx.x & 63, wave = threadIdx.x >> 6;
    const int l15 = lane & 15, quad = lane >> 4;
    const int wr = wave >> 1, wc = wave & 1;
    const int mtile = blockIdx.y * 128, ntile = blockIdx.x * 128;

    f32x4 acc[4][4] = {};
    gemm_core(A, Dc, Bt, Dc, Dc, mtile, ntile, As, Bs, acc, wave, lane);

    #pragma unroll
    for (int mt = 0; mt < 4; mt++) {
        #pragma unroll
        for (int nt = 0; nt < 4; nt++) {
            const int col = ntile + wc * 64 + nt * 16 + l15;
            const float bb = bias[col];
            #pragma unroll
            for (int i = 0; i < 4; i++) {
                const int r = mtile + wr * 64 + mt * 16 + quad * 4 + i;
                C[(long)r * Dc + col] = acc[mt][nt][i] + bb;
            }
        }
    }
}

// ---------------------------------------------------------------------------
// Fused scores + mask + softmax + PV — REGISTER-RESIDENT SCORES, take 2.
// R5 counters exposed the bug: VGPR_Count=52 + WRITE 1.04GB/FETCH 314MB =
// sacc[] spilled to scratch. Cause: phase-1 loop was `#pragma unroll 4`
// (PARTIAL) -> runtime-indexed sacc[t] -> localMem (guide rule #20).
// FIX: FULL unroll so every sacc index is compile-time constant. Everything
// else identical to R5.
// ---------------------------------------------------------------------------
__global__ __launch_bounds__(256, 3)
void attn_fused(const ushort* __restrict__ Q, const ushort* __restrict__ Kp,
                const ushort* __restrict__ Vt, const int* __restrict__ mask,
                float* __restrict__ attn, ushort* __restrict__ Ctx)
{
    __shared__ ushort pB[16 * 1024];   // bf16 P, swizzled: 32 KB
    __shared__ float red[2][4][16];    // cross-wave {max,sum} exchange: 512 B

    const int bh = blockIdx.y;
    const int b = bh >> 4, h = bh & 15;
    const int qbase = blockIdx.x * 16;
    const int lane = threadIdx.x & 63;
    const int wave = threadIdx.x >> 6;
    const int l15 = lane & 15, quad = lane >> 4;

    const ushort* Qh = Q  + (long)b * Sc * Dc + h * HDc;
    const ushort* Kh = Kp + (long)b * Sc * Dc + h * HDc;

    const ushort* qrow = Qh + (long)(qbase + l15) * Dc + quad * 8;
    const bf16x8 a0 = *(const bf16x8*)(qrow);
    const bf16x8 a1 = *(const bf16x8*)(qrow + 32);

    // Phase 1: scores into registers. Wave w covers k-cols [w*256, w*256+256).
    // sacc[t][i] = S[row=quad*4+i][col=(wave*16+t)*16+l15]
    // FULL unroll (static sacc indices -> stays in registers; rule #20).
    f32x4 sacc[16];
    #pragma unroll
    for (int t = 0; t < 16; t++) {
        const int ct = wave * 16 + t;
        const ushort* krow = Kh + (long)(ct * 16 + l15) * Dc + quad * 8;
        const bf16x8 b0 = *(const bf16x8*)(krow);
        const bf16x8 b1 = *(const bf16x8*)(krow + 32);
        f32x4 acc = {};
        acc = __builtin_amdgcn_mfma_f32_16x16x32_bf16(a0, b0, acc, 0, 0, 0);
        acc = __builtin_amdgcn_mfma_f32_16x16x32_bf16(a1, b1, acc, 0, 0, 0);
        sacc[t] = acc;
    }

    // mask bit t for this lane's col (wave*16+t)*16 + l15 (col independent of i)
    unsigned mbits = 0;
    #pragma unroll
    for (int t = 0; t < 16; t++)
        if (mask[b * Sc + (wave * 16 + t) * 16 + l15] == 0) mbits |= (1u << t);

    // Phase 2a: scale + mask in place; per-row max over t (in-lane).
    float mx[4] = { -3.0e38f, -3.0e38f, -3.0e38f, -3.0e38f };
    #pragma unroll
    for (int t = 0; t < 16; t++) {
        const bool msk = (mbits >> t) & 1;
        #pragma unroll
        for (int i = 0; i < 4; i++) {
            float s = sacc[t][i] * 0.125f;          // 1/sqrt(64)
            s = msk ? -1e10f : s;
            sacc[t][i] = s;
            mx[i] = fmaxf(mx[i], s);
        }
    }
    // reduce max over the quad's 16 lanes (bits 0-3 of lane id).
    #pragma unroll
    for (int off = 1; off <= 8; off <<= 1)
        #pragma unroll
        for (int i = 0; i < 4; i++) mx[i] = fmaxf(mx[i], __shfl_xor(mx[i], off, 64));
    // cross-wave max exchange.
    if (l15 == 0)
        #pragma unroll
        for (int i = 0; i < 4; i++) red[0][wave][quad * 4 + i] = mx[i];
    __syncthreads();
    #pragma unroll
    for (int i = 0; i < 4; i++) {
        float g = red[0][0][quad * 4 + i];
        #pragma unroll
        for (int w = 1; w < 4; w++) g = fmaxf(g, red[0][w][quad * 4 + i]);
        mx[i] = g;
    }

    // Phase 2b: exp in place + per-row sum; reduce; cross-wave sum exchange.
    float sm[4] = { 0.f, 0.f, 0.f, 0.f };
    #pragma unroll
    for (int t = 0; t < 16; t++)
        #pragma unroll
        for (int i = 0; i < 4; i++) {
            const float e = __expf(sacc[t][i] - mx[i]);
            sacc[t][i] = e;
            sm[i] += e;
        }
    #pragma unroll
    for (int off = 1; off <= 8; off <<= 1)
        #pragma unroll
        for (int i = 0; i < 4; i++) sm[i] += __shfl_xor(sm[i], off, 64);
    if (l15 == 0)
        #pragma unroll
        for (int i = 0; i < 4; i++) red[1][wave][quad * 4 + i] = sm[i];
    __syncthreads();
    float inv[4];
    #pragma unroll
    for (int i = 0; i < 4; i++) {
        float g = red[1][0][quad * 4 + i] + red[1][1][quad * 4 + i]
                + red[1][2][quad * 4 + i] + red[1][3][quad * 4 + i];
        inv[i] = 1.0f / g;
    }

    // Phase 2c: write fp32 attn (from regs) + bf16 P into swizzled LDS.
    // P row r layout: 8B unit u of logical col-chunk c is at c ^ ((r&7)<<1).
    #pragma unroll
    for (int t = 0; t < 16; t++) {
        const int col = (wave * 16 + t) * 16 + l15;
        #pragma unroll
        for (int i = 0; i < 4; i++) {
            const float p = sacc[t][i] * inv[i];
            const int r = quad * 4 + i;
            attn[((long)bh * Sc + qbase + r) * Sc + col] = p;
            const int u = (col >> 2) ^ ((r & 7) << 1);
            pB[r * 1024 + (u << 2) + (col & 3)] = f2bf(p);
        }
    }
    __syncthreads();

    // Phase 3: ctx = P @ V. Wave w owns d-tile [w*16, w*16+16); 4 indep chains.
    f32x4 pacc[4] = {};
    const ushort* prow = pB + l15 * 1024;
    const int sw2 = (l15 & 7) << 1;
    const ushort* Vh = Vt + (long)bh * HDc * Sc + (long)(wave * 16 + l15) * Sc + quad * 8;
    for (int k0 = 0; k0 < Sc; k0 += 128) {
        bf16x8 af[4], bv4[4];
        #pragma unroll
        for (int u = 0; u < 4; u++) {
            const int k = k0 + u * 32 + quad * 8;               // k>>2 is even
            af[u]  = *(const bf16x8*)(prow + (((k >> 2) ^ sw2) << 2));
            bv4[u] = *(const bf16x8*)(Vh + k0 + u * 32);
        }
        __builtin_amdgcn_s_setprio(1);
        #pragma unroll
        for (int u = 0; u < 4; u++)
            pacc[u] = __builtin_amdgcn_mfma_f32_16x16x32_bf16(af[u], bv4[u], pacc[u], 0, 0, 0);
        __builtin_amdgcn_s_setprio(0);
    }
    f32x4 acc;
    #pragma unroll
    for (int i = 0; i < 4; i++) acc[i] = (pacc[0][i] + pacc[1][i]) + (pacc[2][i] + pacc[3][i]);

    const int dcol = h * HDc + wave * 16 + l15;
    #pragma unroll
    for (int i = 0; i < 4; i++) {
        const int r = qbase + quad * 4 + i;
        Ctx[(long)b * Sc * Dc + (long)r * Dc + dcol] = f2bf(acc[i]);
    }
}

// ---------------------------------------------------------------------------
extern "C" void kernel_launch(void* const* d_in, const int* in_sizes, int n_in,
                              void* d_out, int out_size, void* d_ws, size_t ws_size,
                              hipStream_t stream)
{
    const float* q    = (const float*)d_in[0];
    const float* k    = (const float*)d_in[1];
    const float* v    = (const float*)d_in[2];
    const int*   mask = (const int*)  d_in[3];
    const float* Wq   = (const float*)d_in[4];
    const float* bq   = (const float*)d_in[5];
    const float* Wk   = (const float*)d_in[6];
    const float* bk   = (const float*)d_in[7];
    const float* Wv   = (const float*)d_in[8];
    const float* bv   = (const float*)d_in[9];
    const float* Wo   = (const float*)d_in[10];
    const float* bo   = (const float*)d_in[11];

    ushort* ws  = (ushort*)d_ws;
    ushort* Wob = ws + 3 * BSD + 3 * MM;
    ushort* Qp  = ws + 3 * BSD + 4 * MM;     // projected Q bf16
    ushort* Kpp = Qp + BSD;                  // projected K bf16
    ushort* Vt  = Kpp + BSD;                 // Vt[b,h,d,s] bf16
    ushort* Ctx = Vt + BSD;                  // ctx bf16, (B,S,D) layout

    float* out  = (float*)d_out;             // output 0: (B,S,D) fp32
    float* attn = out + BSD;                 // output 1: (B,H,S,S) fp32

    const dim3 blk(256);

    // fp32 -> bf16 converts (one launch, 7 tensors)
    cvt_all<<<dim3(BSD / (256 * 8), 7), blk, 0, stream>>>(q, k, v, Wq, Wk, Wv, Wo, ws);

    // Q,K,V projections batched: grid (8,32,3) = 768 blocks (~3 blocks/CU).
    gemm_qkv<<<dim3(8, 32, 3), blk, 0, stream>>>(ws, bq, bk, bv, Qp, Vt);

    // Fused scores + softmax + PV: writes attn (fp32 output) and Ctx (bf16).
    attn_fused<<<dim3(Sc / 16, Bc * Hc), blk, 0, stream>>>(Qp, Kpp, Vt, mask, attn, Ctx);

    // out = ctx @ Wo^T + bo (fp32 out).
    gemm_out<<<dim3(8, 32), blk, 0, stream>>>(Ctx, Wob, bo, out);
}